// Round 14
// baseline (99.833 us; speedup 1.0000x reference)
//
#include <hip/hip_runtime.h>

#define N2 128
#define BLOCK 512        // 8 waves; wave w covers j in [16w, 16w+16)
#define APB 256          // anchors per block: 4 per lane
#define WIN 16
#define BAND 3.814697265625e-06f   // 2^-18 relative guard band (rcp err ~2^-21)

__global__ __launch_bounds__(BLOCK, 8) void matcher_kernel(
    const float4* __restrict__ boxes1,
    const float4* __restrict__ boxes2,
    float* __restrict__ out_vals,
    float* __restrict__ out_idx,
    float* __restrict__ out_labels,
    int n1)
{
#pragma clang fp contract(off)
    __shared__ float s_q[8][APB];
    __shared__ int   s_ix[8][APB];

    const int t    = threadIdx.x;
    const int w    = __builtin_amdgcn_readfirstlane(t >> 6); // wave id 0..7
    const int lane = t & 63;
    const int base = blockIdx.x * APB;

    float4 A[4]; float AR[4];
#pragma unroll
    for (int m = 0; m < 4; ++m) {
        const int i = base + lane + m * 64;
        A[m] = boxes1[(i < n1) ? i : 0];
        AR[m] = (A[m].z - A[m].x) * (A[m].w - A[m].y);
    }

    const int j0 = w * WIN;
    // argmax of r = inter/S (S=area1+area2) == argmax of ref IoU (q=r/(1-r)
    // monotone on r in [0,1/2]); top-2 tracked, band test once post-loop.
    float bq[4] = {-1.0f, -1.0f, -1.0f, -1.0f};
    float b2[4] = {-1.0f, -1.0f, -1.0f, -1.0f};
    int   bx[4] = {0, 0, 0, 0};

    // FULL unroll: compiler hoists the 16 uniform float4 loads into
    // s_load_dwordx16 bursts (SGPR-resident window), ONE lgkmcnt wait,
    // then 64 pair-computations with zero memory ops. a2 recomputed from
    // SGPRs (bit-identical to reference's area2) -> no LDS in hot path.
#pragma unroll
    for (int k = 0; k < WIN; ++k) {
        const int j = j0 + k;                  // wave-uniform
        const float4 b = boxes2[j];            // -> SGPR window
        const float a2 = (b.z - b.x) * (b.w - b.y);
#pragma unroll
        for (int m = 0; m < 4; ++m) {
            const float hy = fmaxf(fminf(A[m].z, b.z) - fmaxf(A[m].x, b.x), 0.0f);
            const float hx = fmaxf(fminf(A[m].w, b.w) - fmaxf(A[m].y, b.y), 0.0f);
            const float inter = hy * hx;
            const float S = AR[m] + a2;
            // fmax(...,0) absorbs 0*rcp(0)=NaN (both degenerate) to ref's q=0
            const float q = fmaxf(inter * __builtin_amdgcn_rcpf(S), 0.0f);
            b2[m] = fmaxf(b2[m], fminf(bq[m], q));   // runner-up
            const bool cc = q > bq[m];               // strict > == first-max
            bq[m] = fmaxf(bq[m], q);
            bx[m] = cc ? k : bx[m];                  // inline-const cndmask
        }
    }

    // exact reference-semantics IoU for (anchor m, global box J)
#define REFQ(M_, J, QOUT)                                                  \
    {                                                                      \
        const float4 b = boxes2[(J)];                                      \
        const float wa2 = (b.z - b.x) * (b.w - b.y);                       \
        const float hy = fmaxf(fminf(A[M_].z, b.z) - fmaxf(A[M_].x, b.x), 0.0f); \
        const float hx = fmaxf(fminf(A[M_].w, b.w) - fmaxf(A[M_].y, b.y), 0.0f); \
        const float inter = hy * hx;                                       \
        const float um = fmaxf((AR[M_] + wa2) - inter, 1e-10f);            \
        QOUT = inter / um;                                                 \
    }

#pragma unroll
    for (int m = 0; m < 4; ++m) {
        int bidx = j0 + bx[m];
        const bool slow = (bq[m] > 0.0f) && ((bq[m] - b2[m]) <= bq[m] * BAND);
        if (slow) {
            // rare: exact replay of this wave's 16-box window
            float best = -1.0f; int bxx = j0;
            for (int k = 0; k < WIN; ++k) {
                float qq; REFQ(m, j0 + k, qq)
                if (qq > best) { best = qq; bxx = j0 + k; }
            }
            bidx = bxx;
        }
        // one exact IEEE divide on the winner: bit-exact matched_val partial
        float qe; REFQ(m, bidx, qe)
        s_q[w][lane + m * 64]  = qe;
        s_ix[w][lane + m * 64] = bidx;
    }
    __syncthreads();

    // merge the 8 wave-partials; ascending wave (ascending j-windows) +
    // strict > on EXACT values == global first-max
    if (t < APB) {
        const int ii = base + t;
        if (ii < n1) {
            float q  = s_q[0][t];
            int   ix = s_ix[0][t];
#pragma unroll
            for (int w2 = 1; w2 < 8; ++w2) {
                const float q2 = s_q[w2][t];
                if (q2 > q) { q = q2; ix = s_ix[w2][t]; }
            }
            out_vals[ii]   = q;
            out_idx[ii]    = (float)ix;
            out_labels[ii] = (q >= 0.7f) ? 1.0f : ((q < 0.3f) ? 0.0f : -1.0f);
        }
    }
}

extern "C" void kernel_launch(void* const* d_in, const int* in_sizes, int n_in,
                              void* d_out, int out_size, void* d_ws, size_t ws_size,
                              hipStream_t stream) {
    const float4* boxes1 = (const float4*)d_in[0];
    const float4* boxes2 = (const float4*)d_in[1];
    const int n1 = in_sizes[0] / 4;

    float* out = (float*)d_out;
    float* out_vals   = out;
    float* out_idx    = out + n1;
    float* out_labels = out + 2 * n1;

    const int grid = (n1 + APB - 1) / APB;
    matcher_kernel<<<grid, BLOCK, 0, stream>>>(boxes1, boxes2,
                                               out_vals, out_idx, out_labels, n1);
}

// Round 15
// 26.446 us; speedup vs baseline: 3.7750x; 3.7750x over previous
//
#include <hip/hip_runtime.h>

#define N2 128
#define BLOCK 512        // 8 waves; wave w covers j in [16w, 16w+16)
#define APB 256          // anchors per block: 4 per lane
#define WIN 16
#define BAND 3.814697265625e-06f   // 2^-18 relative guard band (rcp err ~2^-21)

__global__ __launch_bounds__(BLOCK, 8) void matcher_kernel(
    const float4* __restrict__ boxes1,
    const float4* __restrict__ boxes2,
    float* __restrict__ out_vals,
    float* __restrict__ out_idx,
    float* __restrict__ out_labels,
    int n1)
{
#pragma clang fp contract(off)
    __shared__ float s_q[8][APB];
    __shared__ int   s_ix[8][APB];

    const int t    = threadIdx.x;
    const int w    = __builtin_amdgcn_readfirstlane(t >> 6); // wave id 0..7
    const int lane = t & 63;
    const int base = blockIdx.x * APB;

    float4 A[4]; float AR[4];
#pragma unroll
    for (int m = 0; m < 4; ++m) {
        const int i = base + lane + m * 64;
        A[m] = boxes1[(i < n1) ? i : 0];
        AR[m] = (A[m].z - A[m].x) * (A[m].w - A[m].y);
    }

    const int j0 = w * WIN;
    // argmax of r = inter/S (S=area1+area2) == argmax of ref IoU (q=r/(1-r)
    // monotone on r in [0,1/2]); top-2 tracked, band test once post-loop.
    float bq[4] = {-1.0f, -1.0f, -1.0f, -1.0f};
    float b2[4] = {-1.0f, -1.0f, -1.0f, -1.0f};
    int   bx[4] = {0, 0, 0, 0};

    // unroll 8 (R12's proven codegen — NOT 16: full-window hoist spills).
    // a2 recomputed from the SGPR-resident box (bit-identical to reference
    // area2) -> ZERO LDS traffic in the hot loop, no staging sync.
#pragma unroll 8
    for (int k = 0; k < WIN; ++k) {
        const int j = j0 + k;                  // wave-uniform
        const float4 b = boxes2[j];            // uniform -> s_load_dwordx4
        const float a2 = (b.z - b.x) * (b.w - b.y);
#pragma unroll
        for (int m = 0; m < 4; ++m) {
            const float hy = fmaxf(fminf(A[m].z, b.z) - fmaxf(A[m].x, b.x), 0.0f);
            const float hx = fmaxf(fminf(A[m].w, b.w) - fmaxf(A[m].y, b.y), 0.0f);
            const float inter = hy * hx;
            const float S = AR[m] + a2;
            // fmax(...,0) absorbs 0*rcp(0)=NaN (both degenerate) to ref's q=0
            const float q = fmaxf(inter * __builtin_amdgcn_rcpf(S), 0.0f);
            b2[m] = fmaxf(b2[m], fminf(bq[m], q));   // runner-up
            const bool cc = q > bq[m];               // strict > == first-max
            bq[m] = fmaxf(bq[m], q);
            bx[m] = cc ? k : bx[m];                  // inline-const cndmask
        }
    }

    // exact reference-semantics IoU for (anchor m, global box J)
#define REFQ(M_, J, QOUT)                                                  \
    {                                                                      \
        const float4 b = boxes2[(J)];                                      \
        const float wa2 = (b.z - b.x) * (b.w - b.y);                       \
        const float hy = fmaxf(fminf(A[M_].z, b.z) - fmaxf(A[M_].x, b.x), 0.0f); \
        const float hx = fmaxf(fminf(A[M_].w, b.w) - fmaxf(A[M_].y, b.y), 0.0f); \
        const float inter = hy * hx;                                       \
        const float um = fmaxf((AR[M_] + wa2) - inter, 1e-10f);            \
        QOUT = inter / um;                                                 \
    }

#pragma unroll
    for (int m = 0; m < 4; ++m) {
        int bidx = j0 + bx[m];
        const bool slow = (bq[m] > 0.0f) && ((bq[m] - b2[m]) <= bq[m] * BAND);
        if (slow) {
            // rare: exact replay of this wave's 16-box window
            float best = -1.0f; int bxx = j0;
            for (int k = 0; k < WIN; ++k) {
                float qq; REFQ(m, j0 + k, qq)
                if (qq > best) { best = qq; bxx = j0 + k; }
            }
            bidx = bxx;
        }
        // one exact IEEE divide on the winner: bit-exact matched_val partial
        float qe; REFQ(m, bidx, qe)
        s_q[w][lane + m * 64]  = qe;
        s_ix[w][lane + m * 64] = bidx;
    }
    __syncthreads();

    // merge the 8 wave-partials; ascending wave (ascending j-windows) +
    // strict > on EXACT values == global first-max
    if (t < APB) {
        const int ii = base + t;
        if (ii < n1) {
            float q  = s_q[0][t];
            int   ix = s_ix[0][t];
#pragma unroll
            for (int w2 = 1; w2 < 8; ++w2) {
                const float q2 = s_q[w2][t];
                if (q2 > q) { q = q2; ix = s_ix[w2][t]; }
            }
            out_vals[ii]   = q;
            out_idx[ii]    = (float)ix;
            out_labels[ii] = (q >= 0.7f) ? 1.0f : ((q < 0.3f) ? 0.0f : -1.0f);
        }
    }
}

extern "C" void kernel_launch(void* const* d_in, const int* in_sizes, int n_in,
                              void* d_out, int out_size, void* d_ws, size_t ws_size,
                              hipStream_t stream) {
    const float4* boxes1 = (const float4*)d_in[0];
    const float4* boxes2 = (const float4*)d_in[1];
    const int n1 = in_sizes[0] / 4;

    float* out = (float*)d_out;
    float* out_vals   = out;
    float* out_idx    = out + n1;
    float* out_labels = out + 2 * n1;

    const int grid = (n1 + APB - 1) / APB;
    matcher_kernel<<<grid, BLOCK, 0, stream>>>(boxes1, boxes2,
                                               out_vals, out_idx, out_labels, n1);
}

// Round 16
// 25.853 us; speedup vs baseline: 3.8616x; 1.0230x over previous
//
#include <hip/hip_runtime.h>

#define N2 128
#define BLOCK 512        // 8 waves; wave w covers j in [16w, 16w+16)
#define APB 256          // anchors per block: 4 per lane
#define WIN 16
#define BAND 3.814697265625e-06f   // 2^-18 relative guard band (rcp err ~2^-21)

__global__ __launch_bounds__(BLOCK, 8) void matcher_kernel(
    const float4* __restrict__ boxes1,
    const float4* __restrict__ boxes2,
    float* __restrict__ out_vals,
    float* __restrict__ out_idx,
    float* __restrict__ out_labels,
    int n1)
{
#pragma clang fp contract(off)
    __shared__ float s_area2[N2];
    __shared__ float s_q[8][APB];
    __shared__ int   s_ix[8][APB];

    const int t = threadIdx.x;
    if (t < N2) {
        const float4 b = boxes2[t];            // (y1, x1, y2, x2)
        s_area2[t] = (b.z - b.x) * (b.w - b.y);
    }
    __syncthreads();

    const int w    = __builtin_amdgcn_readfirstlane(t >> 6); // wave id 0..7
    const int lane = t & 63;
    const int base = blockIdx.x * APB;

    // 4 anchors per lane, all statically indexed (full unroll -> registers)
    float4 A[4]; float AR[4];
#pragma unroll
    for (int m = 0; m < 4; ++m) {
        const int i = base + lane + m * 64;
        A[m] = boxes1[(i < n1) ? i : 0];
        AR[m] = (A[m].z - A[m].x) * (A[m].w - A[m].y);
    }

    const int j0 = w * WIN;
    // argmax of r = inter/S (S=area1+area2) == argmax of ref IoU (q=r/(1-r)
    // monotone on r in [0,1/2]); top-2 tracked, band test once post-loop.
    float bq[4] = {-1.0f, -1.0f, -1.0f, -1.0f};
    float b2[4] = {-1.0f, -1.0f, -1.0f, -1.0f};
    int   bx[4] = {0, 0, 0, 0};

#pragma unroll 8
    for (int k = 0; k < WIN; ++k) {
        const int j = j0 + k;                  // wave-uniform
        const float4 b = boxes2[j];            // uniform -> s_load_dwordx4
        const float a2 = s_area2[j];           // uniform -> LDS broadcast
#pragma unroll
        for (int m = 0; m < 4; ++m) {
            const float hy = fmaxf(fminf(A[m].z, b.z) - fmaxf(A[m].x, b.x), 0.0f);
            const float hx = fmaxf(fminf(A[m].w, b.w) - fmaxf(A[m].y, b.y), 0.0f);
            const float inter = hy * hx;
            const float S = AR[m] + a2;
            // fmax(...,0) absorbs 0*rcp(0)=NaN (both degenerate) to ref's q=0
            const float q = fmaxf(inter * __builtin_amdgcn_rcpf(S), 0.0f);
            b2[m] = fmaxf(b2[m], fminf(bq[m], q));   // runner-up
            const bool cc = q > bq[m];               // strict > == first-max
            bq[m] = fmaxf(bq[m], q);
            bx[m] = cc ? k : bx[m];                  // inline-const cndmask
        }
    }

    // exact reference-semantics IoU for (anchor m, global box J)
#define REFQ(M_, J, QOUT)                                                  \
    {                                                                      \
        const float4 b = boxes2[(J)];                                      \
        const float wa2 = (b.z - b.x) * (b.w - b.y);                       \
        const float hy = fmaxf(fminf(A[M_].z, b.z) - fmaxf(A[M_].x, b.x), 0.0f); \
        const float hx = fmaxf(fminf(A[M_].w, b.w) - fmaxf(A[M_].y, b.y), 0.0f); \
        const float inter = hy * hx;                                       \
        const float um = fmaxf((AR[M_] + wa2) - inter, 1e-10f);            \
        QOUT = inter / um;                                                 \
    }

#pragma unroll
    for (int m = 0; m < 4; ++m) {
        int bidx = j0 + bx[m];
        const bool slow = (bq[m] > 0.0f) && ((bq[m] - b2[m]) <= bq[m] * BAND);
        if (slow) {
            // rare: exact replay of this wave's 16-box window
            float best = -1.0f; int bxx = j0;
            for (int k = 0; k < WIN; ++k) {
                float qq; REFQ(m, j0 + k, qq)
                if (qq > best) { best = qq; bxx = j0 + k; }
            }
            bidx = bxx;
        }
        // one exact IEEE divide on the winner: bit-exact matched_val partial
        float qe; REFQ(m, bidx, qe)
        s_q[w][lane + m * 64]  = qe;
        s_ix[w][lane + m * 64] = bidx;
    }
    __syncthreads();

    // merge the 8 wave-partials; ascending wave (ascending j-windows) +
    // strict > on EXACT values == global first-max
    if (t < APB) {
        const int ii = base + t;
        if (ii < n1) {
            float q  = s_q[0][t];
            int   ix = s_ix[0][t];
#pragma unroll
            for (int w2 = 1; w2 < 8; ++w2) {
                const float q2 = s_q[w2][t];
                if (q2 > q) { q = q2; ix = s_ix[w2][t]; }
            }
            out_vals[ii]   = q;
            out_idx[ii]    = (float)ix;
            out_labels[ii] = (q >= 0.7f) ? 1.0f : ((q < 0.3f) ? 0.0f : -1.0f);
        }
    }
}

extern "C" void kernel_launch(void* const* d_in, const int* in_sizes, int n_in,
                              void* d_out, int out_size, void* d_ws, size_t ws_size,
                              hipStream_t stream) {
    const float4* boxes1 = (const float4*)d_in[0];
    const float4* boxes2 = (const float4*)d_in[1];
    const int n1 = in_sizes[0] / 4;

    float* out = (float*)d_out;
    float* out_vals   = out;
    float* out_idx    = out + n1;
    float* out_labels = out + 2 * n1;

    const int grid = (n1 + APB - 1) / APB;
    matcher_kernel<<<grid, BLOCK, 0, stream>>>(boxes1, boxes2,
                                               out_vals, out_idx, out_labels, n1);
}